// Round 1
// baseline (894.406 us; speedup 1.0000x reference)
//
#include <hip/hip_runtime.h>

// GraphGenRnn: node-LSTM (2L, HN=128, 64 seqs, 160 steps) -> node_exit/edge_entry
// -> edge-LSTM (2L, HE=16, 10240 seqs, ragged steps) -> heads -> scatter.
// All scatter targets are unique (lower tri from el, upper tri from eu), so
// plain stores; diagonal zeroed separately.

typedef __attribute__((ext_vector_type(8))) short short8;
typedef __attribute__((ext_vector_type(4))) float floatx4;

#define NG 64
#define NMAX 161

__device__ __forceinline__ float sgm(float x) {
  return __builtin_amdgcn_rcpf(1.0f + __expf(-x));
}
__device__ __forceinline__ float tanhf_(float x) {
  return 2.0f * __builtin_amdgcn_rcpf(1.0f + __expf(-2.0f * x)) - 1.0f;
}
__device__ __forceinline__ unsigned short f2b(float x) {
  union { float f; unsigned u; } v; v.f = x;
  unsigned r = v.u + 0x7fffu + ((v.u >> 16) & 1u);   // RNE to bf16
  return (unsigned short)(r >> 16);
}
__device__ __forceinline__ float b2f(unsigned short h) {
  union { unsigned u; float f; } v; v.u = ((unsigned)h) << 16; return v.f;
}

// ---------------------------------------------------------------------------
// Node LSTM: 4 blocks x 512 threads (8 waves). Block b owns genes [16b,16b+16).
// Wave w owns hidden units [16w,16w+16): its 4 gate col-tiles (i,f,g,o), full K.
// Weights live in VGPRs as bf16 MFMA B-fragments (loaded once).
// h state cycles through LDS as bf16; layer-1 A = [h0new | h1] (K=256).
// Writes node_flat[k][u] bf16 with k = (159-s)*64 + gene.
// ---------------------------------------------------------------------------
__global__ __launch_bounds__(512) void node_kernel(
    const float* __restrict__ gene,   // [64][128]
    const float* __restrict__ entw,   // [128][128]
    const float* __restrict__ entb,   // [128]
    const float* __restrict__ nwih,   // [1][512][128]
    const float* __restrict__ nwhh,   // [2][512][128]
    const float* __restrict__ nbih,   // [2][512]
    const float* __restrict__ nbhh,   // [2][512]
    unsigned short* __restrict__ nout) // bf16 [10240][128]
{
  const int tid  = threadIdx.x;
  const int wv   = tid >> 6;
  const int lane = tid & 63;
  const int lo   = lane & 15;
  const int hi   = lane >> 4;
  const int u    = (wv << 4) | lo;   // hidden unit / gate column
  const int nb   = blockIdx.x;

  // padded rows: 136*2=272B (17x16B) and 264*2=528B (33x16B) -> 2-way banks, 16B aligned
  __shared__ __align__(16) unsigned short hA0[16][136];
  __shared__ __align__(16) unsigned short hA1[16][264];

  // ---- persistent B fragments (bf16) ----
  short8 B0[4][4];   // [gate type][K-slice of 32]
  short8 B1[4][8];   // layer1: K=256 = [wih | whh1]
#pragma unroll
  for (int t = 0; t < 4; ++t) {
    const int n = t * 128 + u;
#pragma unroll
    for (int ks = 0; ks < 4; ++ks) {
      const float* src = nwhh + n * 128 + ks * 32 + hi * 8;
      short8 bfr;
#pragma unroll
      for (int jj = 0; jj < 8; ++jj) bfr[jj] = (short)f2b(src[jj]);
      B0[t][ks] = bfr;
    }
#pragma unroll
    for (int ks = 0; ks < 8; ++ks) {
      const int k = ks * 32 + hi * 8;
      const float* src = (ks < 4) ? (nwih + n * 128 + k)
                                  : (nwhh + 512 * 128 + n * 128 + (k - 128));
      short8 bfr;
#pragma unroll
      for (int jj = 0; jj < 8; ++jj) bfr[jj] = (short)f2b(src[jj]);
      B1[t][ks] = bfr;
    }
  }

  const float bi0 = nbih[u]       + nbhh[u];
  const float bf0 = nbih[128 + u] + nbhh[128 + u];
  const float bg0 = nbih[256 + u] + nbhh[256 + u];
  const float bo0 = nbih[384 + u] + nbhh[384 + u];
  const float bi1 = nbih[512 + u]       + nbhh[512 + u];
  const float bf1 = nbih[512 + 128 + u] + nbhh[512 + 128 + u];
  const float bg1 = nbih[512 + 256 + u] + nbhh[512 + 256 + u];
  const float bo1 = nbih[512 + 384 + u] + nbhh[512 + 384 + u];

  // ---- h0 = relu(gene @ entw^T + entb), replicated to both layers ----
  {
    const int q  = tid >> 5;            // 16 genes per block
    const int u4 = (tid & 31) * 4;      // 4 units per thread
    const float* gc = gene + (nb * 16 + q) * 128;
    float acc[4] = { entb[u4], entb[u4 + 1], entb[u4 + 2], entb[u4 + 3] };
    for (int qq = 0; qq < 32; ++qq) {
      const float4 gv = *(const float4*)&gc[qq * 4];
#pragma unroll
      for (int r = 0; r < 4; ++r) {
        const float4 wv2 = *(const float4*)&entw[(u4 + r) * 128 + qq * 4];
        acc[r] += gv.x * wv2.x + gv.y * wv2.y + gv.z * wv2.z + gv.w * wv2.w;
      }
    }
#pragma unroll
    for (int r = 0; r < 4; ++r) {
      const unsigned short hb = f2b(fmaxf(acc[r], 0.0f));
      hA0[q][u4 + r] = hb;
      hA1[q][128 + u4 + r] = hb;
    }
  }

  float c0[4] = {0.f, 0.f, 0.f, 0.f};
  float c1[4] = {0.f, 0.f, 0.f, 0.f};
  __syncthreads();

  const floatx4 binit0[4] = { (floatx4){bi0,bi0,bi0,bi0}, (floatx4){bf0,bf0,bf0,bf0},
                              (floatx4){bg0,bg0,bg0,bg0}, (floatx4){bo0,bo0,bo0,bo0} };
  const floatx4 binit1[4] = { (floatx4){bi1,bi1,bi1,bi1}, (floatx4){bf1,bf1,bf1,bf1},
                              (floatx4){bg1,bg1,bg1,bg1}, (floatx4){bo1,bo1,bo1,bo1} };

  for (int s = 0; s < 160; ++s) {
    // ---------- layer 0: gates = h0 @ whh0^T + b ----------
    floatx4 a0 = binit0[0], a1 = binit0[1], a2 = binit0[2], a3 = binit0[3];
#pragma unroll
    for (int ks = 0; ks < 4; ++ks) {
      const short8 afr = *(const short8*)&hA0[lo][ks * 32 + hi * 8];
      a0 = __builtin_amdgcn_mfma_f32_16x16x32_bf16(afr, B0[0][ks], a0, 0, 0, 0);
      a1 = __builtin_amdgcn_mfma_f32_16x16x32_bf16(afr, B0[1][ks], a1, 0, 0, 0);
      a2 = __builtin_amdgcn_mfma_f32_16x16x32_bf16(afr, B0[2][ks], a2, 0, 0, 0);
      a3 = __builtin_amdgcn_mfma_f32_16x16x32_bf16(afr, B0[3][ks], a3, 0, 0, 0);
    }
    __syncthreads();  // all reads of hA0 done before overwrite
#pragma unroll
    for (int r = 0; r < 4; ++r) {
      const float iv = sgm(a0[r]);
      const float fv = sgm(a1[r]);
      const float gv = tanhf_(a2[r]);
      const float ov = sgm(a3[r]);
      const float cn = fv * c0[r] + iv * gv;
      c0[r] = cn;
      const unsigned short hb = f2b(ov * tanhf_(cn));
      const int q = hi * 4 + r;   // C layout: row = (lane>>4)*4 + reg
      hA0[q][u] = hb;
      hA1[q][u] = hb;
    }
    __syncthreads();

    // ---------- layer 1: gates = [h0new|h1] @ [wih|whh1]^T + b ----------
    a0 = binit1[0]; a1 = binit1[1]; a2 = binit1[2]; a3 = binit1[3];
#pragma unroll
    for (int ks = 0; ks < 8; ++ks) {
      const short8 afr = *(const short8*)&hA1[lo][ks * 32 + hi * 8];
      a0 = __builtin_amdgcn_mfma_f32_16x16x32_bf16(afr, B1[0][ks], a0, 0, 0, 0);
      a1 = __builtin_amdgcn_mfma_f32_16x16x32_bf16(afr, B1[1][ks], a1, 0, 0, 0);
      a2 = __builtin_amdgcn_mfma_f32_16x16x32_bf16(afr, B1[2][ks], a2, 0, 0, 0);
      a3 = __builtin_amdgcn_mfma_f32_16x16x32_bf16(afr, B1[3][ks], a3, 0, 0, 0);
    }
    __syncthreads();
    const size_t obase = (size_t)((159 - s) * 64 + nb * 16) * 128;
#pragma unroll
    for (int r = 0; r < 4; ++r) {
      const float iv = sgm(a0[r]);
      const float fv = sgm(a1[r]);
      const float gv = tanhf_(a2[r]);
      const float ov = sgm(a3[r]);
      const float cn = fv * c1[r] + iv * gv;
      c1[r] = cn;
      const unsigned short hb = f2b(ov * tanhf_(cn));
      const int q = hi * 4 + r;
      hA1[q][128 + u] = hb;
      nout[obase + (size_t)q * 128 + u] = hb;
    }
    __syncthreads();
  }
}

// ---------------------------------------------------------------------------
// Edge: 640 blocks x 256 threads; block b owns sequences k in [16b,16b+16),
// uniform trip count row = 160 - b/4. Thread = (seq sg, unit u). Weights in LDS.
// Computes h0e in-kernel, runs LSTM only for the masked-in steps, fused heads,
// direct scatter stores. Blocks < 64 also zero graph b's diagonal.
// ---------------------------------------------------------------------------
__global__ __launch_bounds__(256) void edge_kernel(
    const unsigned short* __restrict__ nflat, // bf16 [10240][128]
    const float* __restrict__ exw, const float* __restrict__ exb,   // [32][128],[32]
    const float* __restrict__ enw, const float* __restrict__ enb,   // [16][32],[16]
    const float* __restrict__ ewih,  // [1][64][16]
    const float* __restrict__ ewhh,  // [2][64][16]
    const float* __restrict__ ebih, const float* __restrict__ ebhh, // [2][64]
    const float* __restrict__ ee1w, const float* __restrict__ ee1b,
    const float* __restrict__ ee2w, const float* __restrict__ ee2b,
    const float* __restrict__ ef1w, const float* __restrict__ ef1b,
    const float* __restrict__ ef2w, const float* __restrict__ ef2b,
    float* __restrict__ out)
{
  const int tid = threadIdx.x;
  const int sg  = tid >> 4;
  const int u   = tid & 15;
  const int b   = blockIdx.x;
  const int kbase = b * 16;
  const int jrow  = 160 - (b >> 2);   // = row(k) for all k in this block

  __shared__ __align__(16) float s_exw[32][132];
  __shared__ __align__(16) float s_nf[16][132];
  __shared__ __align__(16) float s_enw[16][36];
  __shared__ __align__(16) float s_w0[64][20];
  __shared__ __align__(16) float s_w1[64][36];
  __shared__ __align__(16) float s_ee1[8][20];
  __shared__ __align__(16) float s_ef1[8][20];
  __shared__ __align__(16) float s_ef2[32][8];
  __shared__ __align__(16) float s_ee2[16];
  __shared__ float s_be0[64], s_be1[64];
  __shared__ float s_exb[32], s_enb[16], s_e1b[8], s_e2b[2], s_f1b[8], s_f2b[32];
  __shared__ __align__(16) float h0b[16][20];
  __shared__ __align__(16) float h1b[16][20];
  __shared__ __align__(16) float t1b[16][12];
  __shared__ __align__(16) float t2b[16][12];
  __shared__ __align__(16) float x32[16][36];

  for (int i = tid; i < 32 * 128; i += 256) s_exw[i >> 7][i & 127] = exw[i];
  for (int i = tid; i < 16 * 128; i += 256)
    s_nf[i >> 7][i & 127] = b2f(nflat[(size_t)(kbase + (i >> 7)) * 128 + (i & 127)]);
  for (int i = tid; i < 16 * 32; i += 256) s_enw[i >> 5][i & 31] = enw[i];
  for (int i = tid; i < 64 * 16; i += 256) {
    s_w0[i >> 4][i & 15] = ewhh[i];                 // layer0 whh
    s_w1[i >> 4][i & 15] = ewih[i];                 // layer1 wih
    s_w1[i >> 4][16 + (i & 15)] = ewhh[1024 + i];   // layer1 whh
  }
  for (int i = tid; i < 8 * 16; i += 256) { s_ee1[i >> 4][i & 15] = ee1w[i]; s_ef1[i >> 4][i & 15] = ef1w[i]; }
  for (int i = tid; i < 32 * 8; i += 256) s_ef2[i >> 3][i & 7] = ef2w[i];
  if (tid < 64) { s_be0[tid] = ebih[tid] + ebhh[tid]; s_be1[tid] = ebih[64 + tid] + ebhh[64 + tid]; }
  if (tid < 32) { s_exb[tid] = exb[tid]; s_f2b[tid] = ef2b[tid]; }
  if (tid < 16) { s_enb[tid] = enb[tid]; s_ee2[tid] = ee2w[tid]; }
  if (tid < 8)  { s_e1b[tid] = ee1b[tid]; s_f1b[tid] = ef1b[tid]; }
  if (tid < 2)  s_e2b[tid] = ee2b[tid];

  // zero the (never-written) diagonal; graph g == b for first 64 blocks
  if (b < NG) {
    for (int d = tid; d < NMAX; d += 256) {
      out[(size_t)b * (NMAX * NMAX) + (size_t)d * NMAX + d] = 0.0f;
      float* fb = out + (size_t)NG * NMAX * NMAX
                + ((size_t)b * NMAX * NMAX + (size_t)d * NMAX + d) * 16;
#pragma unroll
      for (int q = 0; q < 16; ++q) fb[q] = 0.0f;
    }
  }
  __syncthreads();

  // ---- h0e = relu(relu(nf @ exw^T + exb) @ enw^T + enb) ----
  {
    float acc0 = s_exb[u], acc1 = s_exb[16 + u];
    for (int qq = 0; qq < 32; ++qq) {
      const float4 nv  = *(const float4*)&s_nf[sg][qq * 4];
      const float4 w0v = *(const float4*)&s_exw[u][qq * 4];
      const float4 w1v = *(const float4*)&s_exw[16 + u][qq * 4];
      acc0 += nv.x * w0v.x + nv.y * w0v.y + nv.z * w0v.z + nv.w * w0v.w;
      acc1 += nv.x * w1v.x + nv.y * w1v.y + nv.z * w1v.z + nv.w * w1v.w;
    }
    x32[sg][u] = fmaxf(acc0, 0.0f);
    x32[sg][16 + u] = fmaxf(acc1, 0.0f);
  }
  __syncthreads();
  float c0 = 0.0f, c1 = 0.0f;
  {
    float acc = s_enb[u];
#pragma unroll
    for (int qq = 0; qq < 8; ++qq) {
      const float4 xv  = *(const float4*)&x32[sg][qq * 4];
      const float4 wv2 = *(const float4*)&s_enw[u][qq * 4];
      acc += xv.x * wv2.x + xv.y * wv2.y + xv.z * wv2.z + xv.w * wv2.w;
    }
    const float h0e = fmaxf(acc, 0.0f);
    h0b[sg][u] = h0e;
    h1b[sg][u] = h0e;
  }
  __syncthreads();

  const int gid = (kbase & 63) + sg;
  float* exi = out + (size_t)gid * (NMAX * NMAX);
  float* fea = out + (size_t)NG * NMAX * NMAX + (size_t)gid * (NMAX * NMAX) * 16;

  for (int s = 0; s < jrow; ++s) {
    float gi, gf, gg, go;
    { // layer 0 gate dots: rows u, 16+u, 32+u, 48+u
      float ai = s_be0[u], af = s_be0[16 + u], ag = s_be0[32 + u], ao = s_be0[48 + u];
#pragma unroll
      for (int qq = 0; qq < 4; ++qq) {
        const float4 hv = *(const float4*)&h0b[sg][qq * 4];
        const float4 wi = *(const float4*)&s_w0[u][qq * 4];
        const float4 wf = *(const float4*)&s_w0[16 + u][qq * 4];
        const float4 wg = *(const float4*)&s_w0[32 + u][qq * 4];
        const float4 wo = *(const float4*)&s_w0[48 + u][qq * 4];
        ai += hv.x * wi.x + hv.y * wi.y + hv.z * wi.z + hv.w * wi.w;
        af += hv.x * wf.x + hv.y * wf.y + hv.z * wf.z + hv.w * wf.w;
        ag += hv.x * wg.x + hv.y * wg.y + hv.z * wg.z + hv.w * wg.w;
        ao += hv.x * wo.x + hv.y * wo.y + hv.z * wo.z + hv.w * wo.w;
      }
      gi = ai; gf = af; gg = ag; go = ao;
    }
    __syncthreads();
    {
      const float iv = sgm(gi), fv = sgm(gf), gv = tanhf_(gg), ov = sgm(go);
      c0 = fv * c0 + iv * gv;
      h0b[sg][u] = ov * tanhf_(c0);
    }
    __syncthreads();
    { // layer 1 gate dots over [h0new | h1]
      float ai = s_be1[u], af = s_be1[16 + u], ag = s_be1[32 + u], ao = s_be1[48 + u];
#pragma unroll
      for (int qq = 0; qq < 4; ++qq) {
        const float4 hv = *(const float4*)&h0b[sg][qq * 4];
        const float4 wi = *(const float4*)&s_w1[u][qq * 4];
        const float4 wf = *(const float4*)&s_w1[16 + u][qq * 4];
        const float4 wg = *(const float4*)&s_w1[32 + u][qq * 4];
        const float4 wo = *(const float4*)&s_w1[48 + u][qq * 4];
        ai += hv.x * wi.x + hv.y * wi.y + hv.z * wi.z + hv.w * wi.w;
        af += hv.x * wf.x + hv.y * wf.y + hv.z * wf.z + hv.w * wf.w;
        ag += hv.x * wg.x + hv.y * wg.y + hv.z * wg.z + hv.w * wg.w;
        ao += hv.x * wo.x + hv.y * wo.y + hv.z * wo.z + hv.w * wo.w;
      }
#pragma unroll
      for (int qq = 0; qq < 4; ++qq) {
        const float4 hv = *(const float4*)&h1b[sg][qq * 4];
        const float4 wi = *(const float4*)&s_w1[u][16 + qq * 4];
        const float4 wf = *(const float4*)&s_w1[16 + u][16 + qq * 4];
        const float4 wg = *(const float4*)&s_w1[32 + u][16 + qq * 4];
        const float4 wo = *(const float4*)&s_w1[48 + u][16 + qq * 4];
        ai += hv.x * wi.x + hv.y * wi.y + hv.z * wi.z + hv.w * wi.w;
        af += hv.x * wf.x + hv.y * wf.y + hv.z * wf.z + hv.w * wf.w;
        ag += hv.x * wg.x + hv.y * wg.y + hv.z * wg.z + hv.w * wg.w;
        ao += hv.x * wo.x + hv.y * wo.y + hv.z * wo.z + hv.w * wo.w;
      }
      gi = ai; gf = af; gg = ag; go = ao;
    }
    __syncthreads();
    {
      const float iv = sgm(gi), fv = sgm(gf), gv = tanhf_(gg), ov = sgm(go);
      c1 = fv * c1 + iv * gv;
      h1b[sg][u] = ov * tanhf_(c1);   // = eh[s]
    }
    __syncthreads();
    // ---- heads ----
    if (u < 8) {
      float a = s_e1b[u];
#pragma unroll
      for (int qq = 0; qq < 4; ++qq) {
        const float4 hv  = *(const float4*)&h1b[sg][qq * 4];
        const float4 wv2 = *(const float4*)&s_ee1[u][qq * 4];
        a += hv.x * wv2.x + hv.y * wv2.y + hv.z * wv2.z + hv.w * wv2.w;
      }
      t1b[sg][u] = fmaxf(a, 0.0f);
    } else {
      const int p = u - 8;
      float a = s_f1b[p];
#pragma unroll
      for (int qq = 0; qq < 4; ++qq) {
        const float4 hv  = *(const float4*)&h1b[sg][qq * 4];
        const float4 wv2 = *(const float4*)&s_ef1[p][qq * 4];
        a += hv.x * wv2.x + hv.y * wv2.y + hv.z * wv2.z + hv.w * wv2.w;
      }
      t2b[sg][p] = fmaxf(a, 0.0f);
    }
    __syncthreads();
    {
      const float4 ta = *(const float4*)&t2b[sg][0];
      const float4 tb = *(const float4*)&t2b[sg][4];
      const float4 wl0 = *(const float4*)&s_ef2[u][0];
      const float4 wl1 = *(const float4*)&s_ef2[u][4];
      const float4 wu0 = *(const float4*)&s_ef2[16 + u][0];
      const float4 wu1 = *(const float4*)&s_ef2[16 + u][4];
      const float fl = s_f2b[u]
          + ta.x * wl0.x + ta.y * wl0.y + ta.z * wl0.z + ta.w * wl0.w
          + tb.x * wl1.x + tb.y * wl1.y + tb.z * wl1.z + tb.w * wl1.w;
      const float fu = s_f2b[16 + u]
          + ta.x * wu0.x + ta.y * wu0.y + ta.z * wu0.z + ta.w * wu0.w
          + tb.x * wu1.x + tb.y * wu1.y + tb.z * wu1.z + tb.w * wu1.w;
      fea[((size_t)jrow * NMAX + s) * 16 + u] = fl;
      fea[((size_t)s * NMAX + jrow) * 16 + u] = fu;
      if (u == 0) {
        float e0 = s_e2b[0], e1 = s_e2b[1];
        const float4 t1a = *(const float4*)&t1b[sg][0];
        const float4 t1c = *(const float4*)&t1b[sg][4];
        const float4 wa0 = *(const float4*)&s_ee2[0];
        const float4 wa1 = *(const float4*)&s_ee2[4];
        const float4 wb0 = *(const float4*)&s_ee2[8];
        const float4 wb1 = *(const float4*)&s_ee2[12];
        e0 += t1a.x * wa0.x + t1a.y * wa0.y + t1a.z * wa0.z + t1a.w * wa0.w
            + t1c.x * wa1.x + t1c.y * wa1.y + t1c.z * wa1.z + t1c.w * wa1.w;
        e1 += t1a.x * wb0.x + t1a.y * wb0.y + t1a.z * wb0.z + t1a.w * wb0.w
            + t1c.x * wb1.x + t1c.y * wb1.y + t1c.z * wb1.z + t1c.w * wb1.w;
        exi[(size_t)jrow * NMAX + s] = sgm(e0);
        exi[(size_t)s * NMAX + jrow] = sgm(e1);
      }
    }
    // no trailing barrier needed: next writes to t1b/h0b are behind >=1 barrier
  }
}

extern "C" void kernel_launch(void* const* d_in, const int* in_sizes, int n_in,
                              void* d_out, int out_size, void* d_ws, size_t ws_size,
                              hipStream_t stream) {
  (void)in_sizes; (void)n_in; (void)out_size; (void)ws_size;
  const float* gene = (const float*)d_in[0];
  const float* entw = (const float*)d_in[1];
  const float* entb = (const float*)d_in[2];
  // d_in[3] node_wih0: multiplies the all-zero input -> unused
  const float* nwih = (const float*)d_in[4];
  const float* nwhh = (const float*)d_in[5];
  const float* nbih = (const float*)d_in[6];
  const float* nbhh = (const float*)d_in[7];
  const float* exw  = (const float*)d_in[8];
  const float* exb  = (const float*)d_in[9];
  const float* enw  = (const float*)d_in[10];
  const float* enb  = (const float*)d_in[11];
  // d_in[12] edge_wih0: unused (zero input)
  const float* ewih = (const float*)d_in[13];
  const float* ewhh = (const float*)d_in[14];
  const float* ebih = (const float*)d_in[15];
  const float* ebhh = (const float*)d_in[16];
  const float* ee1w = (const float*)d_in[17];
  const float* ee1b = (const float*)d_in[18];
  const float* ee2w = (const float*)d_in[19];
  const float* ee2b = (const float*)d_in[20];
  const float* ef1w = (const float*)d_in[21];
  const float* ef1b = (const float*)d_in[22];
  const float* ef2w = (const float*)d_in[23];
  const float* ef2b = (const float*)d_in[24];

  unsigned short* nflat = (unsigned short*)d_ws;  // bf16 [10240][128] = 2.62 MB

  node_kernel<<<4, 512, 0, stream>>>(gene, entw, entb, nwih, nwhh, nbih, nbhh, nflat);
  edge_kernel<<<640, 256, 0, stream>>>(nflat, exw, exb, enw, enb, ewih, ewhh,
                                       ebih, ebhh, ee1w, ee1b, ee2w, ee2b,
                                       ef1w, ef1b, ef2w, ef2b, (float*)d_out);
}